// Round 16
// baseline (252.014 us; speedup 1.0000x reference)
//
#include <hip/hip_runtime.h>
#include <cstdint>

typedef unsigned short u16;
typedef unsigned int u32;
typedef short bf16x8 __attribute__((ext_vector_type(8)));
typedef float f32x4 __attribute__((ext_vector_type(4)));

__device__ __forceinline__ u16 f2bf(float f) {
  unsigned u = __builtin_bit_cast(unsigned, f);
  u = (u + 0x7fffu + ((u >> 16) & 1u)) >> 16;
  return (u16)u;
}

// async global->LDS, 16B per lane. LDS dst = wave-uniform base (HW adds lane*16);
// global src is per-lane.
__device__ __forceinline__ void gload_lds16(const void* g, void* l) {
  __builtin_amdgcn_global_load_lds(
      (const __attribute__((address_space(1))) unsigned int*)g,
      (__attribute__((address_space(3))) unsigned int*)l, 16, 0, 0);
}

// ---------------- Kernel 0: fp32 -> bf16 elementwise ------------------------
__global__ void cvt_f32_bf16(const float* __restrict__ src, u16* __restrict__ dst, int n4) {
  int i = blockIdx.x * 256 + threadIdx.x;
  if (i < n4) {
    float4 v = *reinterpret_cast<const float4*>(src + (size_t)i * 4);
    u16* d = dst + (size_t)i * 4;
    d[0] = f2bf(v.x); d[1] = f2bf(v.y); d[2] = f2bf(v.z); d[3] = f2bf(v.w);
  }
}

// ---------------- Kernel 1: weight transpose (fp32 in, bf16 out) ------------
__global__ void transpose_w_kernel(const float* __restrict__ Wq, const float* __restrict__ Wk,
                                   const float* __restrict__ Wv, u16* __restrict__ Wt) {
  __shared__ u16 tile[64][72];
  const int bid = blockIdx.x;
  const int et = bid & 15;
  const int h  = (bid >> 4) & 15;
  const int p  = bid >> 8;
  const float* W = (p == 0) ? Wq : ((p == 1) ? Wk : Wv);
  const int tid = threadIdx.x;
  for (int idx = tid; idx < 4096; idx += 256) {
    int i = idx >> 6, d = idx & 63;
    tile[d][i] = f2bf(W[(size_t)(h * 1024 + et * 64 + i) * 64 + d]);
  }
  __syncthreads();
  for (int idx = tid; idx < 4096; idx += 256) {
    int dd = idx >> 6, i = idx & 63;
    Wt[(size_t)(p * 1024 + h * 64 + dd) * 1024 + et * 64 + i] = tile[dd][i];
  }
}

// ---------------- Kernel 2/4: GEMM v10 (unchanged from r12) ------------------
template <int N, int MODE>
__global__ __launch_bounds__(512, 1)
void gemm_bt2(const u16* __restrict__ A, const u16* __restrict__ Bt,
              u16* __restrict__ O0, u16* __restrict__ O1, u16* __restrict__ O2,
              float* __restrict__ Of, const float* __restrict__ bias) {
  constexpr int K = 1024, BK = 64, NT = K / BK;
  constexpr int nbn = N / 128;
  constexpr int nwg = 32 * nbn;
  constexpr int ABYTES = 256 * BK * 2;             // 32KB
  constexpr int BUFBYTES = ABYTES + 128 * BK * 2;  // 48KB
  __shared__ char SM[3][BUFBYTES];                 // 144KB ring; reused by epilogue
  const int tid = threadIdx.x;
  const int lane = tid & 63;
  const int wid = tid >> 6;
  const int bid = (blockIdx.x & 7) * (nwg / 8) + (blockIdx.x >> 3);
  const int m0 = (bid / nbn) * 256, n0 = (bid % nbn) * 128;
  const int wm = (wid >> 1) * 64, wn = (wid & 1) * 64;
  const int fr = lane & 15;
  const int fgb = (lane >> 4) << 4;
  const int swz = (fr & 7) << 4;

  f32x4 acc[4][4];
#pragma unroll
  for (int i = 0; i < 4; ++i)
#pragma unroll
    for (int j = 0; j < 4; ++j) acc[i][j] = f32x4{0.f, 0.f, 0.f, 0.f};

  auto stage = [&](char* base, int k0) {
#pragma unroll
    for (int i = 0; i < 4; ++i) {
      int cbase = i * 512 + wid * 64;
      int chunk = cbase + lane;
      int row = chunk >> 3;
      int cole = ((chunk & 7) ^ (row & 7)) << 3;
      gload_lds16(A + (size_t)(m0 + row) * K + k0 + cole, base + cbase * 16);
    }
#pragma unroll
    for (int i = 0; i < 2; ++i) {
      int cbase = i * 512 + wid * 64;
      int chunk = cbase + lane;
      int row = chunk >> 3;
      int cole = ((chunk & 7) ^ (row & 7)) << 3;
      gload_lds16(Bt + (size_t)(n0 + row) * K + k0 + cole, base + ABYTES + cbase * 16);
    }
  };

  stage(&SM[0][0], 0);
  stage(&SM[1][0], BK);
  asm volatile("s_waitcnt vmcnt(6)" ::: "memory");
  __builtin_amdgcn_s_barrier();
  __builtin_amdgcn_sched_barrier(0);

  int bc = 0;
  for (int t = 0; t < NT; ++t) {
    char* Ab = &SM[0][0] + bc * BUFBYTES;
    char* Bb = Ab + ABYTES;
#pragma unroll
    for (int kk = 0; kk < 2; ++kk) {
      const int colb = (kk * 64 + fgb) ^ swz;
      bf16x8 af[4], bf[4];
#pragma unroll
      for (int mi = 0; mi < 4; ++mi)
        af[mi] = *reinterpret_cast<const bf16x8*>(Ab + (wm + mi * 16 + fr) * 128 + colb);
#pragma unroll
      for (int ni = 0; ni < 4; ++ni)
        bf[ni] = *reinterpret_cast<const bf16x8*>(Bb + (wn + ni * 16 + fr) * 128 + colb);
      if (kk == 0 && t + 2 < NT) {
        int bn = bc + 2; if (bn >= 3) bn -= 3;
        stage(&SM[0][0] + bn * BUFBYTES, (t + 2) * BK);
      }
      __builtin_amdgcn_sched_barrier(0);
      __builtin_amdgcn_s_barrier();
      asm volatile("s_waitcnt lgkmcnt(0)" ::: "memory");
      __builtin_amdgcn_sched_barrier(0);
      __builtin_amdgcn_s_setprio(1);
#pragma unroll
      for (int mi = 0; mi < 4; ++mi)
#pragma unroll
        for (int ni = 0; ni < 4; ++ni)
          acc[mi][ni] = __builtin_amdgcn_mfma_f32_16x16x32_bf16(af[mi], bf[ni], acc[mi][ni], 0, 0, 0);
      __builtin_amdgcn_s_setprio(0);
      __builtin_amdgcn_sched_barrier(0);
      if (kk == 1) {
        if (t + 2 < NT)
          asm volatile("s_waitcnt vmcnt(6)" ::: "memory");
        else if (t + 1 < NT)
          asm volatile("s_waitcnt vmcnt(0)" ::: "memory");
      }
      __builtin_amdgcn_s_barrier();
      __builtin_amdgcn_sched_barrier(0);
    }
    ++bc; if (bc == 3) bc = 0;
  }

  const int rq = (lane >> 4) << 2;
  if constexpr (MODE == 0) {
    u16* T = (u16*)&SM[0][0];  // [256][132] u16
#pragma unroll
    for (int ni = 0; ni < 4; ++ni)
#pragma unroll
      for (int mi = 0; mi < 4; ++mi)
#pragma unroll
        for (int r = 0; r < 4; ++r)
          T[(wm + mi * 16 + rq + r) * 132 + wn + ni * 16 + fr] = f2bf(acc[mi][ni][r]);
    __builtin_amdgcn_s_barrier();

    const int pr = n0 >> 10;
    const int hh0 = (n0 >> 6) & 15;
    if (pr < 2) {
      u16* O = (pr == 0) ? O0 : O1;      // [B,H,1024,64]
#pragma unroll
      for (int k = 0; k < 8; ++k) {
        int ch = tid + k * 512;
        int c16 = ch & 7;
        int hhh = (ch >> 3) & 1;
        int m = ch >> 4;
        int mg = m0 + m;
        int b = mg >> 10, t = mg & 1023;
        const u16* src = &T[m * 132 + hhh * 64 + c16 * 8];
        uint2 lo = *(const uint2*)(src);
        uint2 hi = *(const uint2*)(src + 4);
        uint4 val = {lo.x, lo.y, hi.x, hi.y};
        *(uint4*)(O + ((size_t)(b * 16 + hh0 + hhh) * 1024 + t) * 64 + c16 * 8) = val;
      }
    } else {                             // V^T [B,H,64,T]
      const int b = m0 >> 10, tb = m0 & 1023;
#pragma unroll
      for (int k = 0; k < 8; ++k) {
        int ch = tid + k * 512;
        int tc = ch & 31;
        int dd = (ch >> 5) & 63;
        int hhh = ch >> 11;
        u16 tmp[8];
#pragma unroll
        for (int j = 0; j < 8; ++j) tmp[j] = T[(tc * 8 + j) * 132 + hhh * 64 + dd];
        size_t bh = (size_t)(b * 16 + hh0 + hhh);
        *(uint4*)(O2 + (bh * 64 + dd) * 1024 + tb + tc * 8) = *(uint4*)tmp;
      }
    }
  } else {
#pragma unroll
    for (int ni = 0; ni < 4; ++ni) {
      int n = n0 + wn + ni * 16 + fr;
      float bv = bias[n];
#pragma unroll
      for (int mi = 0; mi < 4; ++mi)
#pragma unroll
        for (int r = 0; r < 4; ++r) {
          int m = m0 + wm + mi * 16 + rq + r;
          Of[(size_t)m * N + n] = acc[mi][ni][r] + bv;
        }
    }
  }
}

// ---------------- Kernel 3: causal flash attention (v10) ---------------------
// r12's proven v5 inner body, with SEQUENTIAL wave-level pairing: 32-row unit
// u (work = u/2+1 iters) paired with unit 31-u -> every wave does exactly 17
// iterations, each fully 2-fragment (unlike r13's interleaved pairing whose
// idle fragments still paid per-iteration fixed costs).  1024 blocks, 4/CU
// co-resident, 4 waves/SIMD sustained, zero tail.  tr_read abandoned (2 fails).
__global__ __launch_bounds__(256, 2)
void attn_fwd(const u16* __restrict__ Q, const u16* __restrict__ K,
              const u16* __restrict__ V, u16* __restrict__ O) {
  __shared__ u16 Pl[4][2048];  // per-wave 2 frags x (16x64) bf16, XOR-swizzled
  const int tid = threadIdx.x, lane = tid & 63, w = tid >> 6;
  const int bid = blockIdx.x;
  const int bh = bid & 127;          // low bits -> XCD affinity per head
  const int j  = bid >> 7;           // 0..7
  const int b = bh >> 4, h = bh & 15;
  const int u0 = j * 4 + w;          // this wave's first 32-row unit
  const int fr = lane & 15, fg = lane >> 4, fk = fg << 3;
  const u16* Qb = Q + (size_t)bh * 65536;
  const u16* Kb = K + (size_t)bh * 65536;
  const u16* Vb = V + (size_t)bh * 65536;
  char* Pw = (char*)&Pl[w][0];  // 4KB per wave
  const float cst = 0.125f * 1.44269504088896f;  // hs^-0.5 * log2(e)

  for (int half = 0; half < 2; ++half) {
    const int uu = half ? (31 - u0) : u0;
    const int q0w = uu * 32;

    bf16x8 qf[2][2];
#pragma unroll
    for (int qm = 0; qm < 2; ++qm)
#pragma unroll
      for (int kk = 0; kk < 2; ++kk)
        qf[qm][kk] = *reinterpret_cast<const bf16x8*>(&Qb[(q0w + qm * 16 + fr) * 64 + kk * 32 + fk]);

    f32x4 o[2][4];
    float mrow[2][4], lrow[2][4];  // lrow: per-lane PARTIAL sums
#pragma unroll
    for (int qm = 0; qm < 2; ++qm)
#pragma unroll
      for (int i = 0; i < 4; ++i) {
        o[qm][i] = f32x4{0.f, 0.f, 0.f, 0.f};
        mrow[qm][i] = -1e30f; lrow[qm][i] = 0.f;
      }

    const int stmax = (q0w + 31) >> 6;  // inclusive per-wave bound

    bf16x8 kcur[2][4], knxt[2][4], vf[2][4];
#pragma unroll
    for (int kk = 0; kk < 2; ++kk)
#pragma unroll
      for (int nf = 0; nf < 4; ++nf)
        kcur[kk][nf] = *reinterpret_cast<const bf16x8*>(&Kb[(nf * 16 + fr) * 64 + kk * 32 + fk]);

    for (int st = 0; st <= stmax; ++st) {
      // 1) prefetch next K tile (clamped)
      const u16* Ktn = Kb + (st < stmax ? st + 1 : st) * 4096;
#pragma unroll
      for (int kk = 0; kk < 2; ++kk)
#pragma unroll
        for (int nf = 0; nf < 4; ++nf)
          knxt[kk][nf] = *reinterpret_cast<const bf16x8*>(&Ktn[(nf * 16 + fr) * 64 + kk * 32 + fk]);

      // 2) QK^T
      f32x4 s[2][4];
#pragma unroll
      for (int qm = 0; qm < 2; ++qm)
#pragma unroll
        for (int i = 0; i < 4; ++i) s[qm][i] = f32x4{0.f, 0.f, 0.f, 0.f};
#pragma unroll
      for (int kk = 0; kk < 2; ++kk)
#pragma unroll
        for (int nf = 0; nf < 4; ++nf) {
          s[0][nf] = __builtin_amdgcn_mfma_f32_16x16x32_bf16(qf[0][kk], kcur[kk][nf], s[0][nf], 0, 0, 0);
          s[1][nf] = __builtin_amdgcn_mfma_f32_16x16x32_bf16(qf[1][kk], kcur[kk][nf], s[1][nf], 0, 0, 0);
        }

      // 3) V loads (latency hides under softmax VALU)
#pragma unroll
      for (int kk = 0; kk < 2; ++kk)
#pragma unroll
        for (int df = 0; df < 4; ++df)
          vf[kk][df] = *reinterpret_cast<const bf16x8*>(&Vb[(df * 16 + fr) * 1024 + st * 64 + kk * 32 + fk]);

      // 4) softmax (shuffle-free steady state)
#pragma unroll
      for (int qm = 0; qm < 2; ++qm) {
        const int qb = q0w + qm * 16;
        const bool need_mask = (st * 64 + 63 > qb);  // wave-uniform
        float sv[4][4];
#pragma unroll
        for (int nf = 0; nf < 4; ++nf)
#pragma unroll
          for (int r = 0; r < 4; ++r) {
            float xv = s[qm][nf][r] * cst;
            if (need_mask) {
              int sc = st * 64 + nf * 16 + fr;
              int qr = qb + fg * 4 + r;
              if (sc > qr) xv = -1e30f;
            }
            sv[nf][r] = xv;
          }
        float pmax[4];
#pragma unroll
        for (int r = 0; r < 4; ++r)
          pmax[r] = fmaxf(fmaxf(sv[0][r], sv[1][r]), fmaxf(sv[2][r], sv[3][r]));
        bool grew = (pmax[0] > mrow[qm][0] + 8.f) || (pmax[1] > mrow[qm][1] + 8.f) ||
                    (pmax[2] > mrow[qm][2] + 8.f) || (pmax[3] > mrow[qm][3] + 8.f);
        if (__any(grew)) {  // rare: full row-max reduce + rescale
#pragma unroll
          for (int r = 0; r < 4; ++r) {
            float m = pmax[r];
            m = fmaxf(m, __shfl_xor(m, 1));
            m = fmaxf(m, __shfl_xor(m, 2));
            m = fmaxf(m, __shfl_xor(m, 4));
            m = fmaxf(m, __shfl_xor(m, 8));
            float mnew = fmaxf(mrow[qm][r], m);
            float a = exp2f(mrow[qm][r] - mnew);
            lrow[qm][r] *= a;
            o[qm][0][r] *= a; o[qm][1][r] *= a; o[qm][2][r] *= a; o[qm][3][r] *= a;
            mrow[qm][r] = mnew;
          }
        }
        char* Pq = Pw + qm * 2048;
#pragma unroll
        for (int r = 0; r < 4; ++r) {
          float sum = 0.f;
#pragma unroll
          for (int nf = 0; nf < 4; ++nf) {
            float pv = exp2f(sv[nf][r] - mrow[qm][r]);  // bounded by 2^8
            sum += pv;
            int mm = fg * 4 + r, nn = nf * 16 + fr;
            int byteoff = (mm * 128 + nn * 2) ^ ((mm & 7) << 4);
            *(u16*)(Pq + byteoff) = f2bf(pv);
          }
          lrow[qm][r] += sum;  // partial only; no shuffles
        }
      }

      // 5) PV (same-wave LDS write->read in-order, no barrier)
#pragma unroll
      for (int kk = 0; kk < 2; ++kk) {
        int rb = (fr * 128 + kk * 64 + fg * 16) ^ ((fr & 7) << 4);
        bf16x8 pa0 = *reinterpret_cast<const bf16x8*>(Pw + rb);
        bf16x8 pa1 = *reinterpret_cast<const bf16x8*>(Pw + 2048 + rb);
#pragma unroll
        for (int df = 0; df < 4; ++df) {
          o[0][df] = __builtin_amdgcn_mfma_f32_16x16x32_bf16(pa0, vf[kk][df], o[0][df], 0, 0, 0);
          o[1][df] = __builtin_amdgcn_mfma_f32_16x16x32_bf16(pa1, vf[kk][df], o[1][df], 0, 0, 0);
        }
      }

      // 6) rotate K double-buffer
#pragma unroll
      for (int kk = 0; kk < 2; ++kk)
#pragma unroll
        for (int nf = 0; nf < 4; ++nf) kcur[kk][nf] = knxt[kk][nf];
    }

#pragma unroll
    for (int qm = 0; qm < 2; ++qm)
#pragma unroll
      for (int r = 0; r < 4; ++r) {
        float sum = lrow[qm][r];
        sum += __shfl_xor(sum, 1);
        sum += __shfl_xor(sum, 2);
        sum += __shfl_xor(sum, 4);
        sum += __shfl_xor(sum, 8);
        float inv = 1.0f / sum;
        int t = q0w + qm * 16 + fg * 4 + r;
        size_t base = ((size_t)b * 1024 + t) * 1024 + h * 64;
#pragma unroll
        for (int df = 0; df < 4; ++df) O[base + df * 16 + fr] = f2bf(o[qm][df][r] * inv);
      }
  }
}

// ---------------- launcher ---------------------------------------------------
extern "C" void kernel_launch(void* const* d_in, const int* in_sizes, int n_in,
                              void* d_out, int out_size, void* d_ws, size_t ws_size,
                              hipStream_t stream) {
  (void)in_sizes; (void)n_in; (void)out_size; (void)ws_size;
  const float* x  = (const float*)d_in[0];
  const float* Wq = (const float*)d_in[1];
  const float* Wk = (const float*)d_in[2];
  const float* Wv = (const float*)d_in[3];
  const float* Wp = (const float*)d_in[4];
  const float* bp = (const float*)d_in[5];
  float* out = (float*)d_out;

  char* ws = (char*)d_ws;
  u16* xb  = (u16*)(ws);              // 16MB, reused as Ob after attn input dead
  u16* Ob  = (u16*)(ws);
  u16* Wt  = (u16*)(ws + 16777216);   // 6MB, reused as Wpb
  u16* Wpb = (u16*)(ws + 16777216);
  u16* Qb  = (u16*)(ws + 23068672);   // 16 MB: [B,H,1024,64]
  u16* Kb  = (u16*)(ws + 39845888);   // 16 MB
  u16* Vt  = (u16*)(ws + 56623104);   // 16 MB: [B,H,64,1024]

  cvt_f32_bf16<<<8192, 256, 0, stream>>>(x, xb, 2097152);
  transpose_w_kernel<<<768, 256, 0, stream>>>(Wq, Wk, Wv, Wt);
  gemm_bt2<3072, 0><<<768, 512, 0, stream>>>(xb, Wt, Qb, Kb, Vt, nullptr, nullptr);
  cvt_f32_bf16<<<1024, 256, 0, stream>>>(Wp, Wpb, 262144);
  attn_fwd<<<1024, 256, 0, stream>>>(Qb, Kb, Vt, Ob);
  gemm_bt2<1024, 1><<<256, 512, 0, stream>>>(Ob, Wpb, nullptr, nullptr, nullptr, out, bp);
}

// Round 17
// 186.631 us; speedup vs baseline: 1.3503x; 1.3503x over previous
//
#include <hip/hip_runtime.h>
#include <cstdint>

typedef unsigned short u16;
typedef unsigned int u32;
typedef short bf16x8 __attribute__((ext_vector_type(8)));
typedef float f32x4 __attribute__((ext_vector_type(4)));

__device__ __forceinline__ u16 f2bf(float f) {
  unsigned u = __builtin_bit_cast(unsigned, f);
  u = (u + 0x7fffu + ((u >> 16) & 1u)) >> 16;
  return (u16)u;
}

// async global->LDS, 16B per lane. LDS dst = wave-uniform base (HW adds lane*16);
// global src is per-lane.
__device__ __forceinline__ void gload_lds16(const void* g, void* l) {
  __builtin_amdgcn_global_load_lds(
      (const __attribute__((address_space(1))) unsigned int*)g,
      (__attribute__((address_space(3))) unsigned int*)l, 16, 0, 0);
}

// ---------------- Kernel 0: fp32 -> bf16 elementwise ------------------------
__global__ void cvt_f32_bf16(const float* __restrict__ src, u16* __restrict__ dst, int n4) {
  int i = blockIdx.x * 256 + threadIdx.x;
  if (i < n4) {
    float4 v = *reinterpret_cast<const float4*>(src + (size_t)i * 4);
    u16* d = dst + (size_t)i * 4;
    d[0] = f2bf(v.x); d[1] = f2bf(v.y); d[2] = f2bf(v.z); d[3] = f2bf(v.w);
  }
}

// ---------------- Kernel 1: weight transpose (fp32 in, bf16 out) ------------
__global__ void transpose_w_kernel(const float* __restrict__ Wq, const float* __restrict__ Wk,
                                   const float* __restrict__ Wv, u16* __restrict__ Wt) {
  __shared__ u16 tile[64][72];
  const int bid = blockIdx.x;
  const int et = bid & 15;
  const int h  = (bid >> 4) & 15;
  const int p  = bid >> 8;
  const float* W = (p == 0) ? Wq : ((p == 1) ? Wk : Wv);
  const int tid = threadIdx.x;
  for (int idx = tid; idx < 4096; idx += 256) {
    int i = idx >> 6, d = idx & 63;
    tile[d][i] = f2bf(W[(size_t)(h * 1024 + et * 64 + i) * 64 + d]);
  }
  __syncthreads();
  for (int idx = tid; idx < 4096; idx += 256) {
    int dd = idx >> 6, i = idx & 63;
    Wt[(size_t)(p * 1024 + h * 64 + dd) * 1024 + et * 64 + i] = tile[dd][i];
  }
}

// ---------------- Kernel 2/4: GEMM v10 (unchanged from r12) ------------------
template <int N, int MODE>
__global__ __launch_bounds__(512, 1)
void gemm_bt2(const u16* __restrict__ A, const u16* __restrict__ Bt,
              u16* __restrict__ O0, u16* __restrict__ O1, u16* __restrict__ O2,
              float* __restrict__ Of, const float* __restrict__ bias) {
  constexpr int K = 1024, BK = 64, NT = K / BK;
  constexpr int nbn = N / 128;
  constexpr int nwg = 32 * nbn;
  constexpr int ABYTES = 256 * BK * 2;             // 32KB
  constexpr int BUFBYTES = ABYTES + 128 * BK * 2;  // 48KB
  __shared__ char SM[3][BUFBYTES];                 // 144KB ring; reused by epilogue
  const int tid = threadIdx.x;
  const int lane = tid & 63;
  const int wid = tid >> 6;
  const int bid = (blockIdx.x & 7) * (nwg / 8) + (blockIdx.x >> 3);
  const int m0 = (bid / nbn) * 256, n0 = (bid % nbn) * 128;
  const int wm = (wid >> 1) * 64, wn = (wid & 1) * 64;
  const int fr = lane & 15;
  const int fgb = (lane >> 4) << 4;
  const int swz = (fr & 7) << 4;

  f32x4 acc[4][4];
#pragma unroll
  for (int i = 0; i < 4; ++i)
#pragma unroll
    for (int j = 0; j < 4; ++j) acc[i][j] = f32x4{0.f, 0.f, 0.f, 0.f};

  auto stage = [&](char* base, int k0) {
#pragma unroll
    for (int i = 0; i < 4; ++i) {
      int cbase = i * 512 + wid * 64;
      int chunk = cbase + lane;
      int row = chunk >> 3;
      int cole = ((chunk & 7) ^ (row & 7)) << 3;
      gload_lds16(A + (size_t)(m0 + row) * K + k0 + cole, base + cbase * 16);
    }
#pragma unroll
    for (int i = 0; i < 2; ++i) {
      int cbase = i * 512 + wid * 64;
      int chunk = cbase + lane;
      int row = chunk >> 3;
      int cole = ((chunk & 7) ^ (row & 7)) << 3;
      gload_lds16(Bt + (size_t)(n0 + row) * K + k0 + cole, base + ABYTES + cbase * 16);
    }
  };

  stage(&SM[0][0], 0);
  stage(&SM[1][0], BK);
  asm volatile("s_waitcnt vmcnt(6)" ::: "memory");
  __builtin_amdgcn_s_barrier();
  __builtin_amdgcn_sched_barrier(0);

  int bc = 0;
  for (int t = 0; t < NT; ++t) {
    char* Ab = &SM[0][0] + bc * BUFBYTES;
    char* Bb = Ab + ABYTES;
#pragma unroll
    for (int kk = 0; kk < 2; ++kk) {
      const int colb = (kk * 64 + fgb) ^ swz;
      bf16x8 af[4], bf[4];
#pragma unroll
      for (int mi = 0; mi < 4; ++mi)
        af[mi] = *reinterpret_cast<const bf16x8*>(Ab + (wm + mi * 16 + fr) * 128 + colb);
#pragma unroll
      for (int ni = 0; ni < 4; ++ni)
        bf[ni] = *reinterpret_cast<const bf16x8*>(Bb + (wn + ni * 16 + fr) * 128 + colb);
      if (kk == 0 && t + 2 < NT) {
        int bn = bc + 2; if (bn >= 3) bn -= 3;
        stage(&SM[0][0] + bn * BUFBYTES, (t + 2) * BK);
      }
      __builtin_amdgcn_sched_barrier(0);
      __builtin_amdgcn_s_barrier();
      asm volatile("s_waitcnt lgkmcnt(0)" ::: "memory");
      __builtin_amdgcn_sched_barrier(0);
      __builtin_amdgcn_s_setprio(1);
#pragma unroll
      for (int mi = 0; mi < 4; ++mi)
#pragma unroll
        for (int ni = 0; ni < 4; ++ni)
          acc[mi][ni] = __builtin_amdgcn_mfma_f32_16x16x32_bf16(af[mi], bf[ni], acc[mi][ni], 0, 0, 0);
      __builtin_amdgcn_s_setprio(0);
      __builtin_amdgcn_sched_barrier(0);
      if (kk == 1) {
        if (t + 2 < NT)
          asm volatile("s_waitcnt vmcnt(6)" ::: "memory");
        else if (t + 1 < NT)
          asm volatile("s_waitcnt vmcnt(0)" ::: "memory");
      }
      __builtin_amdgcn_s_barrier();
      __builtin_amdgcn_sched_barrier(0);
    }
    ++bc; if (bc == 3) bc = 0;
  }

  const int rq = (lane >> 4) << 2;
  if constexpr (MODE == 0) {
    u16* T = (u16*)&SM[0][0];  // [256][132] u16
#pragma unroll
    for (int ni = 0; ni < 4; ++ni)
#pragma unroll
      for (int mi = 0; mi < 4; ++mi)
#pragma unroll
        for (int r = 0; r < 4; ++r)
          T[(wm + mi * 16 + rq + r) * 132 + wn + ni * 16 + fr] = f2bf(acc[mi][ni][r]);
    __builtin_amdgcn_s_barrier();

    const int pr = n0 >> 10;
    const int hh0 = (n0 >> 6) & 15;
    if (pr < 2) {
      u16* O = (pr == 0) ? O0 : O1;      // [B,H,1024,64]
#pragma unroll
      for (int k = 0; k < 8; ++k) {
        int ch = tid + k * 512;
        int c16 = ch & 7;
        int hhh = (ch >> 3) & 1;
        int m = ch >> 4;
        int mg = m0 + m;
        int b = mg >> 10, t = mg & 1023;
        const u16* src = &T[m * 132 + hhh * 64 + c16 * 8];
        uint2 lo = *(const uint2*)(src);
        uint2 hi = *(const uint2*)(src + 4);
        uint4 val = {lo.x, lo.y, hi.x, hi.y};
        *(uint4*)(O + ((size_t)(b * 16 + hh0 + hhh) * 1024 + t) * 64 + c16 * 8) = val;
      }
    } else {                             // V^T [B,H,64,T]
      const int b = m0 >> 10, tb = m0 & 1023;
#pragma unroll
      for (int k = 0; k < 8; ++k) {
        int ch = tid + k * 512;
        int tc = ch & 31;
        int dd = (ch >> 5) & 63;
        int hhh = ch >> 11;
        u16 tmp[8];
#pragma unroll
        for (int j = 0; j < 8; ++j) tmp[j] = T[(tc * 8 + j) * 132 + hhh * 64 + dd];
        size_t bh = (size_t)(b * 16 + hh0 + hhh);
        *(uint4*)(O2 + (bh * 64 + dd) * 1024 + tb + tc * 8) = *(uint4*)tmp;
      }
    }
  } else {
#pragma unroll
    for (int ni = 0; ni < 4; ++ni) {
      int n = n0 + wn + ni * 16 + fr;
      float bv = bias[n];
#pragma unroll
      for (int mi = 0; mi < 4; ++mi)
#pragma unroll
        for (int r = 0; r < 4; ++r) {
          int m = m0 + wm + mi * 16 + rq + r;
          Of[(size_t)m * N + n] = acc[mi][ni][r] + bv;
        }
    }
  }
}

// ---------------- Kernel 3: causal flash attention (v11) ---------------------
// v10 body with the COVERAGE FIX: 512 blocks (was 1024 -> every unit computed
// twice; FETCH/WRITE exactly doubled, dur 164us for 2x work).  j = bid>>7 in
// [0,4); wave w handles unit u0 = j*4+w in [0,16) then 31-u0 in [16,32) --
// bijective, every wave exactly ~17 full-2-fragment iterations, zero tail.
__global__ __launch_bounds__(256, 2)
void attn_fwd(const u16* __restrict__ Q, const u16* __restrict__ K,
              const u16* __restrict__ V, u16* __restrict__ O) {
  __shared__ u16 Pl[4][2048];  // per-wave 2 frags x (16x64) bf16, XOR-swizzled
  const int tid = threadIdx.x, lane = tid & 63, w = tid >> 6;
  const int bid = blockIdx.x;
  const int bh = bid & 127;          // low bits -> XCD affinity per head
  const int j  = bid >> 7;           // 0..3
  const int b = bh >> 4, h = bh & 15;
  const int u0 = j * 4 + w;          // 0..15
  const int fr = lane & 15, fg = lane >> 4, fk = fg << 3;
  const u16* Qb = Q + (size_t)bh * 65536;
  const u16* Kb = K + (size_t)bh * 65536;
  const u16* Vb = V + (size_t)bh * 65536;
  char* Pw = (char*)&Pl[w][0];  // 4KB per wave
  const float cst = 0.125f * 1.44269504088896f;  // hs^-0.5 * log2(e)

  for (int half = 0; half < 2; ++half) {
    const int uu = half ? (31 - u0) : u0;
    const int q0w = uu * 32;

    bf16x8 qf[2][2];
#pragma unroll
    for (int qm = 0; qm < 2; ++qm)
#pragma unroll
      for (int kk = 0; kk < 2; ++kk)
        qf[qm][kk] = *reinterpret_cast<const bf16x8*>(&Qb[(q0w + qm * 16 + fr) * 64 + kk * 32 + fk]);

    f32x4 o[2][4];
    float mrow[2][4], lrow[2][4];  // lrow: per-lane PARTIAL sums
#pragma unroll
    for (int qm = 0; qm < 2; ++qm)
#pragma unroll
      for (int i = 0; i < 4; ++i) {
        o[qm][i] = f32x4{0.f, 0.f, 0.f, 0.f};
        mrow[qm][i] = -1e30f; lrow[qm][i] = 0.f;
      }

    const int stmax = (q0w + 31) >> 6;  // inclusive per-wave bound

    bf16x8 kcur[2][4], knxt[2][4], vf[2][4];
#pragma unroll
    for (int kk = 0; kk < 2; ++kk)
#pragma unroll
      for (int nf = 0; nf < 4; ++nf)
        kcur[kk][nf] = *reinterpret_cast<const bf16x8*>(&Kb[(nf * 16 + fr) * 64 + kk * 32 + fk]);

    for (int st = 0; st <= stmax; ++st) {
      // 1) prefetch next K tile (clamped)
      const u16* Ktn = Kb + (st < stmax ? st + 1 : st) * 4096;
#pragma unroll
      for (int kk = 0; kk < 2; ++kk)
#pragma unroll
        for (int nf = 0; nf < 4; ++nf)
          knxt[kk][nf] = *reinterpret_cast<const bf16x8*>(&Ktn[(nf * 16 + fr) * 64 + kk * 32 + fk]);

      // 2) QK^T
      f32x4 s[2][4];
#pragma unroll
      for (int qm = 0; qm < 2; ++qm)
#pragma unroll
        for (int i = 0; i < 4; ++i) s[qm][i] = f32x4{0.f, 0.f, 0.f, 0.f};
#pragma unroll
      for (int kk = 0; kk < 2; ++kk)
#pragma unroll
        for (int nf = 0; nf < 4; ++nf) {
          s[0][nf] = __builtin_amdgcn_mfma_f32_16x16x32_bf16(qf[0][kk], kcur[kk][nf], s[0][nf], 0, 0, 0);
          s[1][nf] = __builtin_amdgcn_mfma_f32_16x16x32_bf16(qf[1][kk], kcur[kk][nf], s[1][nf], 0, 0, 0);
        }

      // 3) V loads (latency hides under softmax VALU)
#pragma unroll
      for (int kk = 0; kk < 2; ++kk)
#pragma unroll
        for (int df = 0; df < 4; ++df)
          vf[kk][df] = *reinterpret_cast<const bf16x8*>(&Vb[(df * 16 + fr) * 1024 + st * 64 + kk * 32 + fk]);

      // 4) softmax (shuffle-free steady state)
#pragma unroll
      for (int qm = 0; qm < 2; ++qm) {
        const int qb = q0w + qm * 16;
        const bool need_mask = (st * 64 + 63 > qb);  // wave-uniform
        float sv[4][4];
#pragma unroll
        for (int nf = 0; nf < 4; ++nf)
#pragma unroll
          for (int r = 0; r < 4; ++r) {
            float xv = s[qm][nf][r] * cst;
            if (need_mask) {
              int sc = st * 64 + nf * 16 + fr;
              int qr = qb + fg * 4 + r;
              if (sc > qr) xv = -1e30f;
            }
            sv[nf][r] = xv;
          }
        float pmax[4];
#pragma unroll
        for (int r = 0; r < 4; ++r)
          pmax[r] = fmaxf(fmaxf(sv[0][r], sv[1][r]), fmaxf(sv[2][r], sv[3][r]));
        bool grew = (pmax[0] > mrow[qm][0] + 8.f) || (pmax[1] > mrow[qm][1] + 8.f) ||
                    (pmax[2] > mrow[qm][2] + 8.f) || (pmax[3] > mrow[qm][3] + 8.f);
        if (__any(grew)) {  // rare: full row-max reduce + rescale
#pragma unroll
          for (int r = 0; r < 4; ++r) {
            float m = pmax[r];
            m = fmaxf(m, __shfl_xor(m, 1));
            m = fmaxf(m, __shfl_xor(m, 2));
            m = fmaxf(m, __shfl_xor(m, 4));
            m = fmaxf(m, __shfl_xor(m, 8));
            float mnew = fmaxf(mrow[qm][r], m);
            float a = exp2f(mrow[qm][r] - mnew);
            lrow[qm][r] *= a;
            o[qm][0][r] *= a; o[qm][1][r] *= a; o[qm][2][r] *= a; o[qm][3][r] *= a;
            mrow[qm][r] = mnew;
          }
        }
        char* Pq = Pw + qm * 2048;
#pragma unroll
        for (int r = 0; r < 4; ++r) {
          float sum = 0.f;
#pragma unroll
          for (int nf = 0; nf < 4; ++nf) {
            float pv = exp2f(sv[nf][r] - mrow[qm][r]);  // bounded by 2^8
            sum += pv;
            int mm = fg * 4 + r, nn = nf * 16 + fr;
            int byteoff = (mm * 128 + nn * 2) ^ ((mm & 7) << 4);
            *(u16*)(Pq + byteoff) = f2bf(pv);
          }
          lrow[qm][r] += sum;  // partial only; no shuffles
        }
      }

      // 5) PV (same-wave LDS write->read in-order, no barrier)
#pragma unroll
      for (int kk = 0; kk < 2; ++kk) {
        int rb = (fr * 128 + kk * 64 + fg * 16) ^ ((fr & 7) << 4);
        bf16x8 pa0 = *reinterpret_cast<const bf16x8*>(Pw + rb);
        bf16x8 pa1 = *reinterpret_cast<const bf16x8*>(Pw + 2048 + rb);
#pragma unroll
        for (int df = 0; df < 4; ++df) {
          o[0][df] = __builtin_amdgcn_mfma_f32_16x16x32_bf16(pa0, vf[kk][df], o[0][df], 0, 0, 0);
          o[1][df] = __builtin_amdgcn_mfma_f32_16x16x32_bf16(pa1, vf[kk][df], o[1][df], 0, 0, 0);
        }
      }

      // 6) rotate K double-buffer
#pragma unroll
      for (int kk = 0; kk < 2; ++kk)
#pragma unroll
        for (int nf = 0; nf < 4; ++nf) kcur[kk][nf] = knxt[kk][nf];
    }

#pragma unroll
    for (int qm = 0; qm < 2; ++qm)
#pragma unroll
      for (int r = 0; r < 4; ++r) {
        float sum = lrow[qm][r];
        sum += __shfl_xor(sum, 1);
        sum += __shfl_xor(sum, 2);
        sum += __shfl_xor(sum, 4);
        sum += __shfl_xor(sum, 8);
        float inv = 1.0f / sum;
        int t = q0w + qm * 16 + fg * 4 + r;
        size_t base = ((size_t)b * 1024 + t) * 1024 + h * 64;
#pragma unroll
        for (int df = 0; df < 4; ++df) O[base + df * 16 + fr] = f2bf(o[qm][df][r] * inv);
      }
  }
}

// ---------------- launcher ---------------------------------------------------
extern "C" void kernel_launch(void* const* d_in, const int* in_sizes, int n_in,
                              void* d_out, int out_size, void* d_ws, size_t ws_size,
                              hipStream_t stream) {
  (void)in_sizes; (void)n_in; (void)out_size; (void)ws_size;
  const float* x  = (const float*)d_in[0];
  const float* Wq = (const float*)d_in[1];
  const float* Wk = (const float*)d_in[2];
  const float* Wv = (const float*)d_in[3];
  const float* Wp = (const float*)d_in[4];
  const float* bp = (const float*)d_in[5];
  float* out = (float*)d_out;

  char* ws = (char*)d_ws;
  u16* xb  = (u16*)(ws);              // 16MB, reused as Ob after attn input dead
  u16* Ob  = (u16*)(ws);
  u16* Wt  = (u16*)(ws + 16777216);   // 6MB, reused as Wpb
  u16* Wpb = (u16*)(ws + 16777216);
  u16* Qb  = (u16*)(ws + 23068672);   // 16 MB: [B,H,1024,64]
  u16* Kb  = (u16*)(ws + 39845888);   // 16 MB
  u16* Vt  = (u16*)(ws + 56623104);   // 16 MB: [B,H,64,1024]

  cvt_f32_bf16<<<8192, 256, 0, stream>>>(x, xb, 2097152);
  transpose_w_kernel<<<768, 256, 0, stream>>>(Wq, Wk, Wv, Wt);
  gemm_bt2<3072, 0><<<768, 512, 0, stream>>>(xb, Wt, Qb, Kb, Vt, nullptr, nullptr);
  cvt_f32_bf16<<<1024, 256, 0, stream>>>(Wp, Wpb, 262144);
  attn_fwd<<<512, 256, 0, stream>>>(Qb, Kb, Vt, Ob);
  gemm_bt2<1024, 1><<<256, 512, 0, stream>>>(Ob, Wpb, nullptr, nullptr, nullptr, out, bp);
}